// Round 8
// baseline (302.094 us; speedup 1.0000x reference)
//
#include <hip/hip_runtime.h>
#include <hip/hip_fp16.h>
#include <math.h>

#define N_NODES   80000
#define NU_NODES  40000
#define E_EDGES   1280000
#define B_PAIRS   8192
#define NEG_SLOPE 0.2f
#define NBUCK     313   // ceil(N_NODES / 256)
#define SCHUNK    2048  // edges per bscatter block (625 blocks -> real occupancy)

// ---------------- row_ptr build (exact-dst histogram + scan) ----------------

__global__ void hist_kernel(const int* __restrict__ dst, int* __restrict__ counts, int E) {
    int e = blockIdx.x * 256 + threadIdx.x;
    if (e < E) atomicAdd(&counts[dst[e]], 1);
}

__global__ void scan_blocks_kernel(const int* __restrict__ counts, int* __restrict__ row_ptr,
                                   int* __restrict__ bsums, int n) {
    __shared__ int tmp[1024];
    int gid = blockIdx.x * 1024 + threadIdx.x;
    int v = (gid < n) ? counts[gid] : 0;
    tmp[threadIdx.x] = v;
    __syncthreads();
    for (int off = 1; off < 1024; off <<= 1) {
        int t = (threadIdx.x >= off) ? tmp[threadIdx.x - off] : 0;
        __syncthreads();
        tmp[threadIdx.x] += t;
        __syncthreads();
    }
    if (gid < n) row_ptr[gid + 1] = tmp[threadIdx.x];
    if (threadIdx.x == 1023) bsums[blockIdx.x] = tmp[1023];
}

__global__ void scan_sums_kernel(int* bsums, int nb) {
    __shared__ int tmp[256];
    int v = (threadIdx.x < nb) ? bsums[threadIdx.x] : 0;
    tmp[threadIdx.x] = v;
    __syncthreads();
    for (int off = 1; off < 256; off <<= 1) {
        int t = (threadIdx.x >= off) ? tmp[threadIdx.x - off] : 0;
        __syncthreads();
        tmp[threadIdx.x] += t;
        __syncthreads();
    }
    if (threadIdx.x < nb) bsums[threadIdx.x] = tmp[threadIdx.x] - v;  // exclusive
}

__global__ void add_offsets_kernel(int* row_ptr, const int* __restrict__ bsums, int n) {
    int gid = blockIdx.x * 256 + threadIdx.x;
    if (gid < n) row_ptr[gid + 1] += bsums[gid >> 10];
    if (gid == 0) row_ptr[0] = 0;
}

// bucket_ptr[b] = row_ptr[b*256] (buckets are 256 consecutive dst nodes; CSR
// offsets monotone) -> no separate bucket histogram/scan passes needed.
__global__ void derive_buckets_kernel(const int* __restrict__ row_ptr,
                                      int* __restrict__ bucket_ptr, int* __restrict__ gfill) {
    int t = blockIdx.x * 256 + threadIdx.x;
    if (t <= NBUCK) {
        int idx = t << 8;
        if (idx > N_NODES) idx = N_NODES;
        int v = row_ptr[idx];
        bucket_ptr[t] = v;
        if (t < NBUCK) gfill[t] = v;
    }
}

// K1: binned scatter of packed (dst,src) into bucket-grouped runs.

__global__ __launch_bounds__(512) void bscatter_kernel(const int* __restrict__ src,
                                                       const int* __restrict__ dst,
                                                       int* __restrict__ gfill,
                                                       unsigned long long* __restrict__ pk,
                                                       int E) {
    __shared__ int histL[NBUCK];
    __shared__ int baseL[NBUCK];
    __shared__ int rankL[NBUCK];
    for (int i = threadIdx.x; i < NBUCK; i += 512) { histL[i] = 0; rankL[i] = 0; }
    __syncthreads();
    int base = blockIdx.x * SCHUNK;
#pragma unroll
    for (int r = 0; r < SCHUNK / 512; ++r) {
        int e = base + r * 512 + threadIdx.x;
        if (e < E) atomicAdd(&histL[dst[e] >> 8], 1);
    }
    __syncthreads();
    for (int i = threadIdx.x; i < NBUCK; i += 512)
        baseL[i] = histL[i] ? atomicAdd(&gfill[i], histL[i]) : 0;
    __syncthreads();
#pragma unroll
    for (int r = 0; r < SCHUNK / 512; ++r) {
        int e = base + r * 512 + threadIdx.x;
        if (e < E) {
            int d = dst[e];
            int b = d >> 8;
            int rk = atomicAdd(&rankL[b], 1);
            pk[baseL[b] + rk] = ((unsigned long long)(unsigned)d << 32) | (unsigned)src[e];
        }
    }
}

// K2: exact scatter within each bucket; one block per bucket.

__global__ __launch_bounds__(256) void escatter_kernel(const unsigned long long* __restrict__ pk,
                                                       const int* __restrict__ bucket_ptr,
                                                       const int* __restrict__ row_ptr,
                                                       int* __restrict__ src_sorted) {
    __shared__ int fillL[256];
    __shared__ int rpL[256];
    int b = blockIdx.x;
    int node0 = b << 8;
    int nn = N_NODES - node0; if (nn > 256) nn = 256;
    fillL[threadIdx.x] = 0;
    rpL[threadIdx.x]   = (threadIdx.x < nn) ? row_ptr[node0 + threadIdx.x] : 0;
    __syncthreads();
    int s = bucket_ptr[b], e = bucket_ptr[b + 1];
    for (int k = s + threadIdx.x; k < e; k += 256) {
        unsigned long long p = pk[k];
        int lo = (int)(p >> 32) & 255;
        int pos = atomicAdd(&fillL[lo], 1);
        src_sorted[rpL[lo] + pos] = (int)(unsigned)p;
    }
}

// ---------------- GEMM + fused attention-dot epilogue ----------------

#define FMA4(dst, av, bv)                 \
    dst.x = fmaf(av, bv.x, dst.x);        \
    dst.y = fmaf(av, bv.y, dst.y);        \
    dst.z = fmaf(av, bv.z, dst.z);        \
    dst.w = fmaf(av, bv.w, dst.w);

#define DOT4(a, b) (a.x * b.x + a.y * b.y + a.z * b.z + a.w * b.w)

struct alignas(8) H4 { __half2 a, b; };
struct alignas(16) H8 { __half2 h[4]; };

template <int K>
__global__ __launch_bounds__(256, 4) void gemm_kernel(const float* __restrict__ A0,
                                                      const float* __restrict__ A1, int split,
                                                      const float* __restrict__ W,
                                                      const float* __restrict__ attS,
                                                      const float* __restrict__ attD,
                                                      __half* __restrict__ hh,
                                                      float* __restrict__ a_s,
                                                      float* __restrict__ a_d) {
    __shared__ float As[32][128];  // As[k][row ^ ((k&7)<<2)] = A[row0+row][k0+k]
    __shared__ float Bs[32][128];  // Bs[k][col]              = W[k0+k][col]
    __shared__ float attL[256];    // [0:128)=attS, [128:256)=attD
    const int tid  = threadIdx.x;
    const int row0 = blockIdx.x * 128;
    const int tc   = tid & 15;
    const int tr   = tid >> 4;

    attL[tid] = (tid < 128) ? attS[tid] : attD[tid - 128];

    const float* aptr[4];
#pragma unroll
    for (int p = 0; p < 4; ++p) {
        int idx  = tid + p * 256;
        int r    = idx >> 3;
        int grow = row0 + r;
        aptr[p] = (grow < split) ? (A0 + (size_t)grow * K) : (A1 + (size_t)(grow - split) * K);
    }

    float4 acc[2][2][4];
#pragma unroll
    for (int a = 0; a < 2; ++a)
#pragma unroll
        for (int b = 0; b < 2; ++b)
#pragma unroll
            for (int i = 0; i < 4; ++i) acc[a][b][i] = make_float4(0.f, 0.f, 0.f, 0.f);

#pragma unroll 1
    for (int k0 = 0; k0 < K; k0 += 32) {
#pragma unroll
        for (int p = 0; p < 4; ++p) {
            int idx = tid + p * 256;
            int r = idx >> 5, c4 = idx & 31;
            *(float4*)&Bs[r][c4 * 4] = *(const float4*)&W[(size_t)(k0 + r) * 128 + c4 * 4];
        }
#pragma unroll
        for (int p = 0; p < 4; ++p) {
            int idx = tid + p * 256;
            int r = idx >> 3, kq = idx & 7;
            float4 v = *(const float4*)&aptr[p][k0 + kq * 4];
            int kk = kq * 4;
            As[kk + 0][r ^ (((kk + 0) & 7) << 2)] = v.x;
            As[kk + 1][r ^ (((kk + 1) & 7) << 2)] = v.y;
            As[kk + 2][r ^ (((kk + 2) & 7) << 2)] = v.z;
            As[kk + 3][r ^ (((kk + 3) & 7) << 2)] = v.w;
        }
        __syncthreads();
#pragma unroll 2
        for (int k = 0; k < 32; ++k) {
            int sw = (k & 7) << 2;
            float4 a0 = *(const float4*)&As[k][(tr * 4) ^ sw];
            float4 a1 = *(const float4*)&As[k][(64 + tr * 4) ^ sw];
            float4 b0 = *(const float4*)&Bs[k][tc * 4];
            float4 b1 = *(const float4*)&Bs[k][64 + tc * 4];
#pragma unroll
            for (int i = 0; i < 4; ++i) {
                float ar0 = ((const float*)&a0)[i];
                float ar1 = ((const float*)&a1)[i];
                FMA4(acc[0][0][i], ar0, b0);
                FMA4(acc[0][1][i], ar0, b1);
                FMA4(acc[1][0][i], ar1, b0);
                FMA4(acc[1][1][i], ar1, b1);
            }
        }
        __syncthreads();
    }

    const float4 vs0 = *(const float4*)&attL[tc * 4];
    const float4 vs1 = *(const float4*)&attL[64 + tc * 4];
    const float4 vd0 = *(const float4*)&attL[128 + tc * 4];
    const float4 vd1 = *(const float4*)&attL[192 + tc * 4];
#pragma unroll
    for (int rh = 0; rh < 2; ++rh)
#pragma unroll
        for (int i = 0; i < 4; ++i) {
            int row = row0 + rh * 64 + tr * 4 + i;
            float4 a0 = acc[rh][0][i];
            float4 a1 = acc[rh][1][i];
            H4 h0, h1;
            h0.a = __float22half2_rn(make_float2(a0.x, a0.y));
            h0.b = __float22half2_rn(make_float2(a0.z, a0.w));
            h1.a = __float22half2_rn(make_float2(a1.x, a1.y));
            h1.b = __float22half2_rn(make_float2(a1.z, a1.w));
            *(H4*)(hh + (size_t)row * 128 + tc * 4)      = h0;
            *(H4*)(hh + (size_t)row * 128 + 64 + tc * 4) = h1;
            float s0 = DOT4(a0, vs0), s1 = DOT4(a1, vs1);
            float d0 = DOT4(a0, vd0), d1 = DOT4(a1, vd1);
#pragma unroll
            for (int o = 1; o < 16; o <<= 1) {
                s0 += __shfl_xor(s0, o);
                s1 += __shfl_xor(s1, o);
                d0 += __shfl_xor(d0, o);
                d1 += __shfl_xor(d1, o);
            }
            if (tc == 0) {
                *(float2*)&a_s[row * 2] = make_float2(s0, s1);
                *(float2*)&a_d[row * 2] = make_float2(d0, d1);
            }
        }
}

// ---------------- GAT aggregation: one WAVE per dst node ----------------
// Softmax phase: lane = edge (deg<=64 fast path). PV phase re-shaped for MLP:
// lane = (row-slot r = lane>>4, channel-group g = lane&15); each lane loads 16B
// (8 fp16 channels) of one row -> one instruction fetches 4 rows (1KB); two
// batches in flight = 2KB/wave. Cross-slot shfl_xor(16/32) reduce at the end.

template <bool CONCAT>
__global__ __launch_bounds__(256) void gat_agg_kernel(const __half* __restrict__ hh,
        const int* __restrict__ row_ptr, const int* __restrict__ src_sorted,
        const float* __restrict__ a_s, const float* __restrict__ a_d,
        const float* __restrict__ bias, float* __restrict__ out) {
    __shared__ int   s_idx[4][64];
    __shared__ float s_w[4][64][2];
    int wid   = threadIdx.x >> 6;
    int lane  = threadIdx.x & 63;
    int dnode = blockIdx.x * 4 + wid;
    if (dnode >= N_NODES) return;
    int start = row_ptr[dnode], end = row_ptr[dnode + 1];
    int deg = end - start;
    float2 ad = *(const float2*)(a_d + dnode * 2);
    float den0 = 0.f, den1 = 0.f;

    if (deg <= 64) {  // fast path
        float v0 = -INFINITY, v1 = -INFINITY;
        int s = 0;
        if (lane < deg) {
            s = src_sorted[start + lane];
            float2 as = *(const float2*)(a_s + s * 2);
            v0 = as.x + ad.x; v0 = v0 > 0.f ? v0 : NEG_SLOPE * v0;
            v1 = as.y + ad.y; v1 = v1 > 0.f ? v1 : NEG_SLOPE * v1;
        }
        float m0 = v0, m1 = v1;
        for (int o = 32; o; o >>= 1) {
            m0 = fmaxf(m0, __shfl_xor(m0, o));
            m1 = fmaxf(m1, __shfl_xor(m1, o));
        }
        if (lane < deg) {
            float w0 = __expf(v0 - m0), w1 = __expf(v1 - m1);
            den0 = w0; den1 = w1;
            s_idx[wid][lane] = s;
            s_w[wid][lane][0] = w0;
            s_w[wid][lane][1] = w1;
        }
        for (int o = 32; o; o >>= 1) {
            den0 += __shfl_xor(den0, o);
            den1 += __shfl_xor(den1, o);
        }
        __builtin_amdgcn_wave_barrier();  // s_w/s_idx visible wave-wide (single wave writes/reads)

        // ---- PV: 4 rows per batch, 16B/lane ----
        const int g = lane & 15;      // channel group: channels 8g..8g+7
        const int r = lane >> 4;      // row slot
        const int head = g >> 3;
        float accf[8] = {0,0,0,0,0,0,0,0};
        const H8* h8 = (const H8*)hh;
        for (int j = 0; j < deg; j += 8) {
            int   row0i = j + r,     row1i = j + 4 + r;
            bool  val0 = row0i < deg, val1 = row1i < deg;
            if (val0) {
                int   si = s_idx[wid][row0i];
                float w  = s_w[wid][row0i][head];
                H8 hv = h8[(size_t)si * 16 + g];
#pragma unroll
                for (int q = 0; q < 4; ++q) {
                    float2 f = __half22float2(hv.h[q]);
                    accf[q * 2]     = fmaf(w, f.x, accf[q * 2]);
                    accf[q * 2 + 1] = fmaf(w, f.y, accf[q * 2 + 1]);
                }
            }
            if (val1) {
                int   si = s_idx[wid][row1i];
                float w  = s_w[wid][row1i][head];
                H8 hv = h8[(size_t)si * 16 + g];
#pragma unroll
                for (int q = 0; q < 4; ++q) {
                    float2 f = __half22float2(hv.h[q]);
                    accf[q * 2]     = fmaf(w, f.x, accf[q * 2]);
                    accf[q * 2 + 1] = fmaf(w, f.y, accf[q * 2 + 1]);
                }
            }
        }
        // reduce across the 4 row slots (bits 4,5 of lane)
#pragma unroll
        for (int q = 0; q < 8; ++q) {
            accf[q] += __shfl_xor(accf[q], 16);
            accf[q] += __shfl_xor(accf[q], 32);
        }
        float inv = 1.f / ((head ? den1 : den0) + 1e-16f);
        if (CONCAT) {
            if (r == 0) {
                float4 o0, o1;
                const float4 b0v = *(const float4*)&bias[g * 8];
                const float4 b1v = *(const float4*)&bias[g * 8 + 4];
                o0.x = accf[0] * inv + b0v.x; o0.y = accf[1] * inv + b0v.y;
                o0.z = accf[2] * inv + b0v.z; o0.w = accf[3] * inv + b0v.w;
                o1.x = accf[4] * inv + b1v.x; o1.y = accf[5] * inv + b1v.y;
                o1.z = accf[6] * inv + b1v.z; o1.w = accf[7] * inv + b1v.w;
                *(float4*)&out[(size_t)dnode * 128 + g * 8]     = o0;
                *(float4*)&out[(size_t)dnode * 128 + g * 8 + 4] = o1;
            }
        } else {
            // divide by own head's denom, then average with the other head (g ^ 8)
            float rr[8];
#pragma unroll
            for (int q = 0; q < 8; ++q) rr[q] = accf[q] * inv;
#pragma unroll
            for (int q = 0; q < 8; ++q) {
                float other = __shfl_xor(rr[q], 8);
                rr[q] = 0.5f * (rr[q] + other);
            }
            if (r == 0 && g < 8) {
                float4 o0, o1;
                const float4 b0v = *(const float4*)&bias[g * 8];
                const float4 b1v = *(const float4*)&bias[g * 8 + 4];
                o0.x = rr[0] + b0v.x; o0.y = rr[1] + b0v.y;
                o0.z = rr[2] + b0v.z; o0.w = rr[3] + b0v.w;
                o1.x = rr[4] + b1v.x; o1.y = rr[5] + b1v.y;
                o1.z = rr[6] + b1v.z; o1.w = rr[7] + b1v.w;
                *(float4*)&out[(size_t)dnode * 64 + g * 8]     = o0;
                *(float4*)&out[(size_t)dnode * 64 + g * 8 + 4] = o1;
            }
        }
    } else {  // general path (vanishingly rare for Poisson(16))
        int hh_head = lane >> 5;
        float2 acc = {0.f, 0.f};
        const __half2* h2 = (const __half2*)hh;
        float m0 = -INFINITY, m1 = -INFINITY;
        for (int k = start + lane; k < end; k += 64) {
            int s = src_sorted[k];
            float2 as = *(const float2*)(a_s + s * 2);
            float v0 = as.x + ad.x; v0 = v0 > 0.f ? v0 : NEG_SLOPE * v0;
            float v1 = as.y + ad.y; v1 = v1 > 0.f ? v1 : NEG_SLOPE * v1;
            m0 = fmaxf(m0, v0); m1 = fmaxf(m1, v1);
        }
        for (int o = 32; o; o >>= 1) {
            m0 = fmaxf(m0, __shfl_xor(m0, o));
            m1 = fmaxf(m1, __shfl_xor(m1, o));
        }
        for (int c0 = start; c0 < end; c0 += 64) {
            int len = min(64, end - c0);
            if (lane < len) {
                int s = src_sorted[c0 + lane];
                float2 as = *(const float2*)(a_s + s * 2);
                float v0 = as.x + ad.x; v0 = v0 > 0.f ? v0 : NEG_SLOPE * v0;
                float v1 = as.y + ad.y; v1 = v1 > 0.f ? v1 : NEG_SLOPE * v1;
                float w0 = __expf(v0 - m0), w1 = __expf(v1 - m1);
                den0 += w0; den1 += w1;
                s_idx[wid][lane] = s;
                s_w[wid][lane][0] = w0;
                s_w[wid][lane][1] = w1;
            }
            for (int j = 0; j < len; ++j) {
                int  si = s_idx[wid][j];
                float w = s_w[wid][j][hh_head];
                float2 v = __half22float2(h2[(size_t)si * 64 + lane]);
                acc.x = fmaf(w, v.x, acc.x);
                acc.y = fmaf(w, v.y, acc.y);
            }
        }
        for (int o = 32; o; o >>= 1) {
            den0 += __shfl_xor(den0, o);
            den1 += __shfl_xor(den1, o);
        }
        float inv = 1.f / ((hh_head ? den1 : den0) + 1e-16f);
        float2 r2 = {acc.x * inv, acc.y * inv};
        if (CONCAT) {
            float2 b = *(const float2*)(bias + lane * 2);
            float2 o2 = {r2.x + b.x, r2.y + b.y};
            *(float2*)(out + (size_t)dnode * 128 + lane * 2) = o2;
        } else {
            float ox = __shfl_xor(r2.x, 32);
            float oy = __shfl_xor(r2.y, 32);
            if (lane < 32) {
                float2 b = *(const float2*)(bias + lane * 2);
                float2 o2 = {0.5f * (r2.x + ox) + b.x, 0.5f * (r2.y + oy) + b.y};
                *(float2*)(out + (size_t)dnode * 64 + lane * 2) = o2;
            }
        }
    }
}

// ---------------- final pair dot ----------------

__global__ void pair_dot_kernel(const float* __restrict__ emb, const int* __restrict__ ui,
                                const int* __restrict__ ii, float* __restrict__ out, int B) {
    int w    = blockIdx.x * 4 + (threadIdx.x >> 6);
    int lane = threadIdx.x & 63;
    if (w >= B) return;
    float a = emb[(size_t)ui[w] * 64 + lane];
    float b = emb[(size_t)(NU_NODES + ii[w]) * 64 + lane];
    float p = a * b;
    for (int o = 32; o; o >>= 1) p += __shfl_xor(p, o);
    if (lane == 0) out[w] = p;
}

extern "C" void kernel_launch(void* const* d_in, const int* in_sizes, int n_in,
                              void* d_out, int out_size, void* d_ws, size_t ws_size,
                              hipStream_t stream) {
    const float* Gu       = (const float*)d_in[0];
    const float* Gi       = (const float*)d_in[1];
    const float* W0       = (const float*)d_in[2];
    const float* att_src0 = (const float*)d_in[3];
    const float* att_dst0 = (const float*)d_in[4];
    const float* b0       = (const float*)d_in[5];
    const float* W1       = (const float*)d_in[6];
    const float* att_src1 = (const float*)d_in[7];
    const float* att_dst1 = (const float*)d_in[8];
    const float* b1       = (const float*)d_in[9];
    const int* edge_index = (const int*)d_in[10];
    const int* user_idx   = (const int*)d_in[11];
    const int* item_idx   = (const int*)d_in[12];
    float* outp           = (float*)d_out;

    const int N = N_NODES, E = E_EDGES;
    char* wsp = (char*)d_ws;
    auto alloc = [&](size_t bytes) {
        void* p = wsp;
        wsp += (bytes + 255) & ~(size_t)255;
        return p;
    };
    float*  emb = (float*)alloc((size_t)N * 64 * 4);    // final embeddings
    __half* hh  = (__half*)alloc((size_t)N * 128 * 2);  // fp16 h (both layers)
    float*  x1  = (float*)alloc((size_t)N * 128 * 4);   // layer0 output (f32)
    float*  a_s = (float*)alloc((size_t)N * 2 * 4);
    float*  a_d = (float*)alloc((size_t)N * 2 * 4);
    int* row_ptr    = (int*)alloc((size_t)(N + 1) * 4);
    int* counts     = (int*)alloc((size_t)N * 4);
    int* bsums      = (int*)alloc(256 * 4);
    int* src_sorted = (int*)alloc((size_t)E * 4);
    int* bucket_ptr  = (int*)alloc((NBUCK + 1) * 4);
    int* gfill       = (int*)alloc((NBUCK + 1) * 4);
    // pk only lives during CSR build; x1 only after -> overlay
    unsigned long long* pk = (unsigned long long*)x1;

    const int* esrc = edge_index;
    const int* edst = edge_index + E;

    // row_ptr (exact-dst histogram + hierarchical scan)
    hipMemsetAsync(counts, 0, (size_t)N * 4, stream);
    hist_kernel<<<E / 256, 256, 0, stream>>>(edst, counts, E);
    int nb = (N + 1023) / 1024;
    scan_blocks_kernel<<<nb, 1024, 0, stream>>>(counts, row_ptr, bsums, N);
    scan_sums_kernel<<<1, 256, 0, stream>>>(bsums, nb);
    add_offsets_kernel<<<(N + 255) / 256, 256, 0, stream>>>(row_ptr, bsums, N);
    derive_buckets_kernel<<<(NBUCK + 256) / 256, 256, 0, stream>>>(row_ptr, bucket_ptr, gfill);

    // binned scatter -> src_sorted (CSR adjacency by dst)
    bscatter_kernel<<<(E + SCHUNK - 1) / SCHUNK, 512, 0, stream>>>(esrc, edst, gfill, pk, E);
    escatter_kernel<<<NBUCK, 256, 0, stream>>>(pk, bucket_ptr, row_ptr, src_sorted);

    // layer 0 (A read directly from Gu/Gi; h fp16 + att dots fused)
    gemm_kernel<64><<<N / 128, 256, 0, stream>>>(Gu, Gi, NU_NODES, W0, att_src0, att_dst0,
                                                 hh, a_s, a_d);
    gat_agg_kernel<true><<<(N + 3) / 4, 256, 0, stream>>>(hh, row_ptr, src_sorted, a_s, a_d,
                                                          b0, x1);

    // layer 1
    gemm_kernel<128><<<N / 128, 256, 0, stream>>>(x1, x1, N, W1, att_src1, att_dst1,
                                                  hh, a_s, a_d);
    gat_agg_kernel<false><<<(N + 3) / 4, 256, 0, stream>>>(hh, row_ptr, src_sorted, a_s, a_d,
                                                           b1, emb);

    // final dot
    pair_dot_kernel<<<B_PAIRS / 4, 256, 0, stream>>>(emb, user_idx, item_idx, outp, B_PAIRS);
}

// Round 9
// 266.625 us; speedup vs baseline: 1.1330x; 1.1330x over previous
//
#include <hip/hip_runtime.h>
#include <hip/hip_fp16.h>
#include <math.h>

#define N_NODES   80000
#define NU_NODES  40000
#define E_EDGES   1280000
#define B_PAIRS   8192
#define NEG_SLOPE 0.2f
#define NBUCK     313   // ceil(N_NODES / 256)
#define SCHUNK    2048  // edges per bscatter block

typedef _Float16 half8 __attribute__((ext_vector_type(8)));
typedef float    f32x4 __attribute__((ext_vector_type(4)));

// ---------------- row_ptr build (exact-dst histogram + scan) ----------------

__global__ void hist_kernel(const int* __restrict__ dst, int* __restrict__ counts, int E) {
    int e = blockIdx.x * 256 + threadIdx.x;
    if (e < E) atomicAdd(&counts[dst[e]], 1);
}

__global__ void scan_blocks_kernel(const int* __restrict__ counts, int* __restrict__ row_ptr,
                                   int* __restrict__ bsums, int n) {
    __shared__ int tmp[1024];
    int gid = blockIdx.x * 1024 + threadIdx.x;
    int v = (gid < n) ? counts[gid] : 0;
    tmp[threadIdx.x] = v;
    __syncthreads();
    for (int off = 1; off < 1024; off <<= 1) {
        int t = (threadIdx.x >= off) ? tmp[threadIdx.x - off] : 0;
        __syncthreads();
        tmp[threadIdx.x] += t;
        __syncthreads();
    }
    if (gid < n) row_ptr[gid + 1] = tmp[threadIdx.x];
    if (threadIdx.x == 1023) bsums[blockIdx.x] = tmp[1023];
}

__global__ void scan_sums_kernel(int* bsums, int nb) {
    __shared__ int tmp[256];
    int v = (threadIdx.x < nb) ? bsums[threadIdx.x] : 0;
    tmp[threadIdx.x] = v;
    __syncthreads();
    for (int off = 1; off < 256; off <<= 1) {
        int t = (threadIdx.x >= off) ? tmp[threadIdx.x - off] : 0;
        __syncthreads();
        tmp[threadIdx.x] += t;
        __syncthreads();
    }
    if (threadIdx.x < nb) bsums[threadIdx.x] = tmp[threadIdx.x] - v;  // exclusive
}

__global__ void add_offsets_kernel(int* row_ptr, const int* __restrict__ bsums, int n) {
    int gid = blockIdx.x * 256 + threadIdx.x;
    if (gid < n) row_ptr[gid + 1] += bsums[gid >> 10];
    if (gid == 0) row_ptr[0] = 0;
}

__global__ void derive_buckets_kernel(const int* __restrict__ row_ptr,
                                      int* __restrict__ bucket_ptr, int* __restrict__ gfill) {
    int t = blockIdx.x * 256 + threadIdx.x;
    if (t <= NBUCK) {
        int idx = t << 8;
        if (idx > N_NODES) idx = N_NODES;
        int v = row_ptr[idx];
        bucket_ptr[t] = v;
        if (t < NBUCK) gfill[t] = v;
    }
}

__global__ __launch_bounds__(512) void bscatter_kernel(const int* __restrict__ src,
                                                       const int* __restrict__ dst,
                                                       int* __restrict__ gfill,
                                                       unsigned long long* __restrict__ pk,
                                                       int E) {
    __shared__ int histL[NBUCK];
    __shared__ int baseL[NBUCK];
    __shared__ int rankL[NBUCK];
    for (int i = threadIdx.x; i < NBUCK; i += 512) { histL[i] = 0; rankL[i] = 0; }
    __syncthreads();
    int base = blockIdx.x * SCHUNK;
#pragma unroll
    for (int r = 0; r < SCHUNK / 512; ++r) {
        int e = base + r * 512 + threadIdx.x;
        if (e < E) atomicAdd(&histL[dst[e] >> 8], 1);
    }
    __syncthreads();
    for (int i = threadIdx.x; i < NBUCK; i += 512)
        baseL[i] = histL[i] ? atomicAdd(&gfill[i], histL[i]) : 0;
    __syncthreads();
#pragma unroll
    for (int r = 0; r < SCHUNK / 512; ++r) {
        int e = base + r * 512 + threadIdx.x;
        if (e < E) {
            int d = dst[e];
            int b = d >> 8;
            int rk = atomicAdd(&rankL[b], 1);
            pk[baseL[b] + rk] = ((unsigned long long)(unsigned)d << 32) | (unsigned)src[e];
        }
    }
}

__global__ __launch_bounds__(256) void escatter_kernel(const unsigned long long* __restrict__ pk,
                                                       const int* __restrict__ bucket_ptr,
                                                       const int* __restrict__ row_ptr,
                                                       int* __restrict__ src_sorted) {
    __shared__ int fillL[256];
    __shared__ int rpL[256];
    int b = blockIdx.x;
    int node0 = b << 8;
    int nn = N_NODES - node0; if (nn > 256) nn = 256;
    fillL[threadIdx.x] = 0;
    rpL[threadIdx.x]   = (threadIdx.x < nn) ? row_ptr[node0 + threadIdx.x] : 0;
    __syncthreads();
    int s = bucket_ptr[b], e = bucket_ptr[b + 1];
    for (int k = s + threadIdx.x; k < e; k += 256) {
        unsigned long long p = pk[k];
        int lo = (int)(p >> 32) & 255;
        int pos = atomicAdd(&fillL[lo], 1);
        src_sorted[rpL[lo] + pos] = (int)(unsigned)p;
    }
}

// ---------------- MFMA f16 GEMM + fused attention-dot epilogue ----------------
// [M,K]@[K,128] -> h fp16 + a_s/a_d. Block = 128 rows x 128 cols, 4 waves,
// wave = 32 rows. mfma_f32_16x16x32_f16; W pre-transposed to LDS f16 [col][K+8];
// A staged per 32-k chunk into [128][40] f16. C/D layout: col=lane&15,
// row=(lane>>4)*4+reg (HW-verified). A/B k-permutation cancels in the dot.

template <int K, bool AF32>
__global__ __launch_bounds__(256) void gemm_mfma(const void* __restrict__ A0v,
                                                 const void* __restrict__ A1v, int split,
                                                 const float* __restrict__ W,
                                                 const float* __restrict__ attS,
                                                 const float* __restrict__ attD,
                                                 __half* __restrict__ hh,
                                                 float* __restrict__ a_s,
                                                 float* __restrict__ a_d) {
    constexpr int BSTR   = K + 8;                    // Bsm col stride (halves)
    constexpr int BSM_SZ = 128 * BSTR * 2;
    constexpr int EPI_SZ = 128 * 136 * 2;
    constexpr int ATT_OFF = (10240 + BSM_SZ > EPI_SZ) ? (10240 + BSM_SZ) : EPI_SZ;
    __shared__ __align__(16) char lds[ATT_OFF + 1024];
    _Float16* Asm  = (_Float16*)lds;                 // [128][40], chunk of 32 k
    _Float16* Bsm  = (_Float16*)(lds + 10240);       // [col][K+8]
    _Float16* epi  = (_Float16*)lds;                 // [128][136] epilogue overlay
    float*    attL = (float*)(lds + ATT_OFF);        // [0:128)=attS [128:256)=attD

    const int tid    = threadIdx.x;
    const int w      = tid >> 6;
    const int l      = tid & 63;
    const int l15    = l & 15;
    const int g      = l >> 4;
    const int blkrow = blockIdx.x * 128;

    attL[tid] = (tid < 128) ? attS[tid] : attD[tid - 128];

    // stage W -> Bsm (f32->f16, transposed)
    for (int idx = tid; idx < K * 32; idx += 256) {
        int k = idx >> 5, c4 = idx & 31;
        float4 wv = *(const float4*)&W[(size_t)k * 128 + c4 * 4];
        Bsm[(c4 * 4 + 0) * BSTR + k] = (_Float16)wv.x;
        Bsm[(c4 * 4 + 1) * BSTR + k] = (_Float16)wv.y;
        Bsm[(c4 * 4 + 2) * BSTR + k] = (_Float16)wv.z;
        Bsm[(c4 * 4 + 3) * BSTR + k] = (_Float16)wv.w;
    }

    // per-thread A staging rows (2 units: idx = tid + p*256; row = idx>>2)
    const void* rowp[2];
#pragma unroll
    for (int p = 0; p < 2; ++p) {
        int idx = tid + p * 256;
        int row = idx >> 2;
        int grow = blkrow + row;
        if (AF32) {
            const float* A0 = (const float*)A0v;
            const float* A1 = (const float*)A1v;
            rowp[p] = (grow < split) ? (const void*)(A0 + (size_t)grow * K)
                                     : (const void*)(A1 + (size_t)(grow - split) * K);
        } else {
            rowp[p] = (const void*)((const _Float16*)A0v + (size_t)grow * K);
        }
    }

    auto stageA = [&](int c) {
#pragma unroll
        for (int p = 0; p < 2; ++p) {
            int idx = tid + p * 256;
            int row = idx >> 2, kq = idx & 3;
            half8 hv;
            if (AF32) {
                const float* ap = (const float*)rowp[p];
                float4 v0 = *(const float4*)&ap[c * 32 + kq * 8];
                float4 v1 = *(const float4*)&ap[c * 32 + kq * 8 + 4];
                hv[0] = (_Float16)v0.x; hv[1] = (_Float16)v0.y;
                hv[2] = (_Float16)v0.z; hv[3] = (_Float16)v0.w;
                hv[4] = (_Float16)v1.x; hv[5] = (_Float16)v1.y;
                hv[6] = (_Float16)v1.z; hv[7] = (_Float16)v1.w;
            } else {
                const _Float16* ap = (const _Float16*)rowp[p];
                hv = *(const half8*)&ap[c * 32 + kq * 8];
            }
            *(half8*)&Asm[row * 40 + kq * 8] = hv;
        }
    };

    f32x4 acc[2][8];
#pragma unroll
    for (int rt = 0; rt < 2; ++rt)
#pragma unroll
        for (int ct = 0; ct < 8; ++ct) acc[rt][ct] = (f32x4){0.f, 0.f, 0.f, 0.f};

    constexpr int CH = K / 32;
    stageA(0);
    __syncthreads();
#pragma unroll
    for (int c = 0; c < CH; ++c) {
        half8 a0 = *(const half8*)&Asm[(w * 32 + l15) * 40 + g * 8];
        half8 a1 = *(const half8*)&Asm[(w * 32 + 16 + l15) * 40 + g * 8];
#pragma unroll
        for (int ct = 0; ct < 8; ++ct) {
            half8 b = *(const half8*)&Bsm[(ct * 16 + l15) * BSTR + c * 32 + g * 8];
            acc[0][ct] = __builtin_amdgcn_mfma_f32_16x16x32_f16(a0, b, acc[0][ct], 0, 0, 0);
            acc[1][ct] = __builtin_amdgcn_mfma_f32_16x16x32_f16(a1, b, acc[1][ct], 0, 0, 0);
        }
        __syncthreads();
        if (c + 1 < CH) {
            stageA(c + 1);
            __syncthreads();
        }
    }

    // attention dots from f32 fragments: lane covers rows g*4+reg, col l15 of each tile
#pragma unroll
    for (int rt = 0; rt < 2; ++rt)
#pragma unroll
        for (int reg = 0; reg < 4; ++reg) {
            float s0 = 0.f, s1 = 0.f, d0 = 0.f, d1 = 0.f;
#pragma unroll
            for (int ct = 0; ct < 4; ++ct) {
                float v = acc[rt][ct][reg];
                s0 = fmaf(v, attL[ct * 16 + l15], s0);
                d0 = fmaf(v, attL[128 + ct * 16 + l15], d0);
            }
#pragma unroll
            for (int ct = 4; ct < 8; ++ct) {
                float v = acc[rt][ct][reg];
                s1 = fmaf(v, attL[ct * 16 + l15], s1);
                d1 = fmaf(v, attL[128 + ct * 16 + l15], d1);
            }
#pragma unroll
            for (int o = 1; o < 16; o <<= 1) {
                s0 += __shfl_xor(s0, o); s1 += __shfl_xor(s1, o);
                d0 += __shfl_xor(d0, o); d1 += __shfl_xor(d1, o);
            }
            if (l15 == 0) {
                int row = blkrow + w * 32 + rt * 16 + g * 4 + reg;
                *(float2*)&a_s[row * 2] = make_float2(s0, s1);
                *(float2*)&a_d[row * 2] = make_float2(d0, d1);
            }
        }

    // h store via LDS transpose (coalesced 16B global stores)
#pragma unroll
    for (int rt = 0; rt < 2; ++rt)
#pragma unroll
        for (int ct = 0; ct < 8; ++ct)
#pragma unroll
            for (int reg = 0; reg < 4; ++reg)
                epi[(w * 32 + rt * 16 + g * 4 + reg) * 136 + ct * 16 + l15] =
                    (_Float16)acc[rt][ct][reg];
    __syncthreads();
#pragma unroll
    for (int p = 0; p < 8; ++p) {
        int idx = tid + p * 256;
        int row = idx >> 4, c8 = idx & 15;
        *(half8*)&hh[(size_t)(blkrow + row) * 128 + c8 * 8] =
            *(const half8*)&epi[row * 136 + c8 * 8];
    }
}

// ---------------- GAT aggregation: one WAVE per dst node, both heads ----------------
// (R7 structure: lane = channel pair; j-loop unrolled x4 for gather MLP.)
// CONCAT writes fp16 (layer-1 GEMM input), final layer writes f32.

template <bool CONCAT>
__global__ __launch_bounds__(256) void gat_agg_kernel(const __half* __restrict__ hh,
        const int* __restrict__ row_ptr, const int* __restrict__ src_sorted,
        const float* __restrict__ a_s, const float* __restrict__ a_d,
        const float* __restrict__ bias, void* __restrict__ outv) {
    __shared__ int   s_idx[4][64];
    __shared__ float s_w[4][64][2];
    int wid   = threadIdx.x >> 6;
    int lane  = threadIdx.x & 63;
    int dnode = blockIdx.x * 4 + wid;
    if (dnode >= N_NODES) return;
    int start = row_ptr[dnode], end = row_ptr[dnode + 1];
    int deg = end - start;
    float2 ad = *(const float2*)(a_d + dnode * 2);
    int hh_head = lane >> 5;
    float2 acc = {0.f, 0.f};
    float den0 = 0.f, den1 = 0.f;
    const __half2* h2 = (const __half2*)hh;

    if (deg <= 64) {  // fast path
        float v0 = -INFINITY, v1 = -INFINITY;
        int s = 0;
        if (lane < deg) {
            s = src_sorted[start + lane];
            float2 as = *(const float2*)(a_s + s * 2);
            v0 = as.x + ad.x; v0 = v0 > 0.f ? v0 : NEG_SLOPE * v0;
            v1 = as.y + ad.y; v1 = v1 > 0.f ? v1 : NEG_SLOPE * v1;
        }
        float m0 = v0, m1 = v1;
        for (int o = 32; o; o >>= 1) {
            m0 = fmaxf(m0, __shfl_xor(m0, o));
            m1 = fmaxf(m1, __shfl_xor(m1, o));
        }
        if (lane < deg) {
            float w0 = __expf(v0 - m0), w1 = __expf(v1 - m1);
            den0 = w0; den1 = w1;
            s_idx[wid][lane] = s;
            s_w[wid][lane][0] = w0;
            s_w[wid][lane][1] = w1;
        }
        int j = 0;
#pragma unroll 1
        for (; j + 4 <= deg; j += 4) {
            int   si0 = s_idx[wid][j + 0], si1 = s_idx[wid][j + 1];
            int   si2 = s_idx[wid][j + 2], si3 = s_idx[wid][j + 3];
            float w0 = s_w[wid][j + 0][hh_head], w1 = s_w[wid][j + 1][hh_head];
            float w2 = s_w[wid][j + 2][hh_head], w3 = s_w[wid][j + 3][hh_head];
            float2 q0 = __half22float2(h2[(size_t)si0 * 64 + lane]);
            float2 q1 = __half22float2(h2[(size_t)si1 * 64 + lane]);
            float2 q2 = __half22float2(h2[(size_t)si2 * 64 + lane]);
            float2 q3 = __half22float2(h2[(size_t)si3 * 64 + lane]);
            acc.x = fmaf(w0, q0.x, acc.x); acc.y = fmaf(w0, q0.y, acc.y);
            acc.x = fmaf(w1, q1.x, acc.x); acc.y = fmaf(w1, q1.y, acc.y);
            acc.x = fmaf(w2, q2.x, acc.x); acc.y = fmaf(w2, q2.y, acc.y);
            acc.x = fmaf(w3, q3.x, acc.x); acc.y = fmaf(w3, q3.y, acc.y);
        }
        for (; j < deg; ++j) {
            int  si = s_idx[wid][j];
            float w = s_w[wid][j][hh_head];
            float2 v = __half22float2(h2[(size_t)si * 64 + lane]);
            acc.x = fmaf(w, v.x, acc.x);
            acc.y = fmaf(w, v.y, acc.y);
        }
    } else {  // general path (rare for Poisson(16))
        float m0 = -INFINITY, m1 = -INFINITY;
        for (int k = start + lane; k < end; k += 64) {
            int s = src_sorted[k];
            float2 as = *(const float2*)(a_s + s * 2);
            float v0 = as.x + ad.x; v0 = v0 > 0.f ? v0 : NEG_SLOPE * v0;
            float v1 = as.y + ad.y; v1 = v1 > 0.f ? v1 : NEG_SLOPE * v1;
            m0 = fmaxf(m0, v0); m1 = fmaxf(m1, v1);
        }
        for (int o = 32; o; o >>= 1) {
            m0 = fmaxf(m0, __shfl_xor(m0, o));
            m1 = fmaxf(m1, __shfl_xor(m1, o));
        }
        for (int c0 = start; c0 < end; c0 += 64) {
            int len = min(64, end - c0);
            if (lane < len) {
                int s = src_sorted[c0 + lane];
                float2 as = *(const float2*)(a_s + s * 2);
                float v0 = as.x + ad.x; v0 = v0 > 0.f ? v0 : NEG_SLOPE * v0;
                float v1 = as.y + ad.y; v1 = v1 > 0.f ? v1 : NEG_SLOPE * v1;
                float w0 = __expf(v0 - m0), w1 = __expf(v1 - m1);
                den0 += w0; den1 += w1;
                s_idx[wid][lane] = s;
                s_w[wid][lane][0] = w0;
                s_w[wid][lane][1] = w1;
            }
            for (int j = 0; j < len; ++j) {
                int  si = s_idx[wid][j];
                float w = s_w[wid][j][hh_head];
                float2 v = __half22float2(h2[(size_t)si * 64 + lane]);
                acc.x = fmaf(w, v.x, acc.x);
                acc.y = fmaf(w, v.y, acc.y);
            }
        }
    }

    for (int o = 32; o; o >>= 1) {
        den0 += __shfl_xor(den0, o);
        den1 += __shfl_xor(den1, o);
    }
    float inv = 1.f / ((hh_head ? den1 : den0) + 1e-16f);
    float2 r = {acc.x * inv, acc.y * inv};

    if (CONCAT) {
        __half* out = (__half*)outv;
        float2 b = *(const float2*)(bias + lane * 2);
        __half2 o2 = __floats2half2_rn(r.x + b.x, r.y + b.y);
        *(__half2*)(out + (size_t)dnode * 128 + lane * 2) = o2;
    } else {
        float* out = (float*)outv;
        float ox = __shfl_xor(r.x, 32);
        float oy = __shfl_xor(r.y, 32);
        if (lane < 32) {
            float2 b = *(const float2*)(bias + lane * 2);
            float2 o2 = {0.5f * (r.x + ox) + b.x, 0.5f * (r.y + oy) + b.y};
            *(float2*)(out + (size_t)dnode * 64 + lane * 2) = o2;
        }
    }
}

// ---------------- final pair dot ----------------

__global__ void pair_dot_kernel(const float* __restrict__ emb, const int* __restrict__ ui,
                                const int* __restrict__ ii, float* __restrict__ out, int B) {
    int w    = blockIdx.x * 4 + (threadIdx.x >> 6);
    int lane = threadIdx.x & 63;
    if (w >= B) return;
    float a = emb[(size_t)ui[w] * 64 + lane];
    float b = emb[(size_t)(NU_NODES + ii[w]) * 64 + lane];
    float p = a * b;
    for (int o = 32; o; o >>= 1) p += __shfl_xor(p, o);
    if (lane == 0) out[w] = p;
}

extern "C" void kernel_launch(void* const* d_in, const int* in_sizes, int n_in,
                              void* d_out, int out_size, void* d_ws, size_t ws_size,
                              hipStream_t stream) {
    const float* Gu       = (const float*)d_in[0];
    const float* Gi       = (const float*)d_in[1];
    const float* W0       = (const float*)d_in[2];
    const float* att_src0 = (const float*)d_in[3];
    const float* att_dst0 = (const float*)d_in[4];
    const float* b0       = (const float*)d_in[5];
    const float* W1       = (const float*)d_in[6];
    const float* att_src1 = (const float*)d_in[7];
    const float* att_dst1 = (const float*)d_in[8];
    const float* b1       = (const float*)d_in[9];
    const int* edge_index = (const int*)d_in[10];
    const int* user_idx   = (const int*)d_in[11];
    const int* item_idx   = (const int*)d_in[12];
    float* outp           = (float*)d_out;

    const int N = N_NODES, E = E_EDGES;
    char* wsp = (char*)d_ws;
    auto alloc = [&](size_t bytes) {
        void* p = wsp;
        wsp += (bytes + 255) & ~(size_t)255;
        return p;
    };
    float*  emb = (float*)alloc((size_t)N * 64 * 4);    // final embeddings (f32)
    __half* hh  = (__half*)alloc((size_t)N * 128 * 2);  // fp16 h (both layers)
    __half* x1h = (__half*)alloc((size_t)N * 128 * 2);  // layer0 output (fp16)
    float*  a_s = (float*)alloc((size_t)N * 2 * 4);
    float*  a_d = (float*)alloc((size_t)N * 2 * 4);
    int* row_ptr    = (int*)alloc((size_t)(N + 1) * 4);
    int* counts     = (int*)alloc((size_t)N * 4);
    int* bsums      = (int*)alloc(256 * 4);
    int* src_sorted = (int*)alloc((size_t)E * 4);
    int* bucket_ptr  = (int*)alloc((NBUCK + 1) * 4);
    int* gfill       = (int*)alloc((NBUCK + 1) * 4);
    // pk only lives during CSR build; x1h only written after -> overlay
    unsigned long long* pk = (unsigned long long*)x1h;

    const int* esrc = edge_index;
    const int* edst = edge_index + E;

    // row_ptr (exact-dst histogram + hierarchical scan)
    hipMemsetAsync(counts, 0, (size_t)N * 4, stream);
    hist_kernel<<<E / 256, 256, 0, stream>>>(edst, counts, E);
    int nb = (N + 1023) / 1024;
    scan_blocks_kernel<<<nb, 1024, 0, stream>>>(counts, row_ptr, bsums, N);
    scan_sums_kernel<<<1, 256, 0, stream>>>(bsums, nb);
    add_offsets_kernel<<<(N + 255) / 256, 256, 0, stream>>>(row_ptr, bsums, N);
    derive_buckets_kernel<<<(NBUCK + 256) / 256, 256, 0, stream>>>(row_ptr, bucket_ptr, gfill);

    // binned scatter -> src_sorted (CSR adjacency by dst)
    bscatter_kernel<<<(E + SCHUNK - 1) / SCHUNK, 512, 0, stream>>>(esrc, edst, gfill, pk, E);
    escatter_kernel<<<NBUCK, 256, 0, stream>>>(pk, bucket_ptr, row_ptr, src_sorted);

    // layer 0: MFMA GEMM (f32 inputs cast to f16) + fused att dots
    gemm_mfma<64, true><<<N / 128, 256, 0, stream>>>(Gu, Gi, NU_NODES, W0, att_src0, att_dst0,
                                                     hh, a_s, a_d);
    gat_agg_kernel<true><<<(N + 3) / 4, 256, 0, stream>>>(hh, row_ptr, src_sorted, a_s, a_d,
                                                          b0, x1h);

    // layer 1: MFMA GEMM (fp16 input)
    gemm_mfma<128, false><<<N / 128, 256, 0, stream>>>(x1h, x1h, N, W1, att_src1, att_dst1,
                                                       hh, a_s, a_d);
    gat_agg_kernel<false><<<(N + 3) / 4, 256, 0, stream>>>(hh, row_ptr, src_sorted, a_s, a_d,
                                                           b1, emb);

    // final dot
    pair_dot_kernel<<<B_PAIRS / 4, 256, 0, stream>>>(emb, user_idx, item_idx, outp, B_PAIRS);
}